// Round 9
// baseline (1850.926 us; speedup 1.0000x reference)
//
#include <hip/hip_runtime.h>
#include <hip/hip_bf16.h>

// ---------------- workspace layout (float offsets) ----------------
// xdT  [32,1024,64]       q/k/v [32,1024,64]      att  [32,1024,64]
// spart[32,16,1024]; dwt alias (first 1M); wT_c/wT_t at +1M; attT at +2M
// score [32,1024]   idx [32,256]
// cout [8,256,64,64]      y     [8,256,64,64]     t1/coutT [8,256,64,64]
constexpr size_t OFF_XD    = 0;
constexpr size_t OFF_Q     = 2097152;
constexpr size_t OFF_K     = 4194304;
constexpr size_t OFF_V     = 6291456;
constexpr size_t OFF_ATT   = 8388608;
constexpr size_t OFF_SPART = 10485760;
constexpr size_t OFF_SCORE = 14680064;
constexpr size_t OFF_IDX   = 14712832;
constexpr size_t OFF_COUT  = 14721024;
constexpr size_t OFF_Y     = 23109632;
constexpr size_t OFF_T1    = 31498240;
constexpr size_t WS_FLOATS = 39886848;

// ---------------- 0a. transpose down_w [co][ci][kh][kw] -> dwt [ci][kk][co] ----
__global__ __launch_bounds__(256) void k_wt_dn(const float* __restrict__ w,
                                               float* __restrict__ dwt) {
  int idx = blockIdx.x * 256 + threadIdx.x;   // 1,048,576
  int co = idx & 255;
  int kk = (idx >> 8) & 15;
  int ci = idx >> 12;
  dwt[((size_t)(ci * 16 + kk)) * 256 + co] = w[((size_t)(co * 256 + ci)) * 16 + kk];
}

// ---------------- 0b. transpose up_w [ci][co][kh][kw] -> wt [cls][tap][ci][co] --
__global__ __launch_bounds__(256) void k_wt_up(const float* __restrict__ w,
                                               float* __restrict__ wt) {
  int idx = blockIdx.x * 256 + threadIdx.x;   // 1,048,576
  int co = idx & 255;
  int ci = (idx >> 8) & 255;
  int tp = idx >> 16;                         // 0..15
  int cls = tp >> 2, tap = tp & 3;
  int r = cls >> 1, s = cls & 1;
  int kh = (tap < 2) ? (r ? 0 : 1) : (r ? 2 : 3);
  int kw = ((tap & 1) == 0) ? (s ? 0 : 1) : (s ? 2 : 3);
  wt[idx] = w[((size_t)(ci * 256 + co)) * 16 + kh * 4 + kw];
}

// ---------------- 0c. transpose qkv W [192][64] -> wT [64][192] ----------------
__global__ __launch_bounds__(256) void k_wt_qkv(const float* __restrict__ W,
                                                float* __restrict__ wT) {
  int i = blockIdx.x * 256 + threadIdx.x;   // 12288
  if (i < 12288) {
    int e = i >> 6, d = i & 63;
    wT[d * 192 + e] = W[i];
  }
}

// ---------------- 1. down conv v4: per-lane px, SGPR weights -------------------
__global__ __launch_bounds__(256) void k_conv_down4(const float* __restrict__ x,
    const float* __restrict__ dwt, const float* __restrict__ bias,
    float* __restrict__ xdT) {
  int blk = blockIdx.x;            // ((b*4 + cg)*16 + ihp)
  int ihp = blk & 15;
  int cg = (blk >> 4) & 3;
  int b = blk >> 6;
  int oh0 = ihp * 2;
  int t = threadIdx.x;
  int wv = t >> 6, lane = t & 63;
  int co0w = __builtin_amdgcn_readfirstlane(cg * 64 + wv * 16);
  int i_loc = lane >> 5;           // 0..1 (oh row)
  int ow = lane & 31;

  __shared__ float xs[4][6][68];   // even stride -> float2 aligned

  float acc[16];
#pragma unroll
  for (int cc = 0; cc < 16; ++cc) acc[cc] = bias[co0w + cc];

  const float* xb = x + (size_t)b * 256 * 4096;

  for (int ci0 = 0; ci0 < 256; ci0 += 4) {
    __syncthreads();
    for (int idx = t; idx < 4 * 6 * 68; idx += 256) {
      int cl = idx / 408;
      int rem = idx - cl * 408;
      int row = rem / 68;
      int col = rem - row * 68;
      int ih = oh0 * 2 - 1 + row;
      int iw = col - 1;
      float v = 0.f;
      if ((unsigned)ih < 64u && (unsigned)iw < 64u)
        v = xb[(size_t)(ci0 + cl) * 4096 + ih * 64 + iw];
      xs[cl][row][col] = v;
    }
    __syncthreads();
#pragma unroll
    for (int cl = 0; cl < 4; ++cl) {
      int ci = ci0 + cl;
      float xv[4][4];
#pragma unroll
      for (int kh = 0; kh < 4; ++kh) {
        const float* rp = &xs[cl][2 * i_loc + kh][2 * ow];
        float2 p0 = *(const float2*)(rp);
        float2 p1 = *(const float2*)(rp + 2);
        xv[kh][0] = p0.x; xv[kh][1] = p0.y; xv[kh][2] = p1.x; xv[kh][3] = p1.y;
      }
      const float* wrow = dwt + (size_t)ci * 4096 + co0w;
#pragma unroll
      for (int kh = 0; kh < 4; ++kh)
#pragma unroll
        for (int kw = 0; kw < 4; ++kw) {
          const float* wp = wrow + (kh * 4 + kw) * 256;
          float xvv = xv[kh][kw];
#pragma unroll
          for (int g = 0; g < 4; ++g) {
            float4 wq = *(const float4*)(wp + g * 4);
            acc[g * 4 + 0] = fmaf(xvv, wq.x, acc[g * 4 + 0]);
            acc[g * 4 + 1] = fmaf(xvv, wq.y, acc[g * 4 + 1]);
            acc[g * 4 + 2] = fmaf(xvv, wq.z, acc[g * 4 + 2]);
            acc[g * 4 + 3] = fmaf(xvv, wq.w, acc[g * 4 + 3]);
          }
        }
    }
  }
  int bn = b * 4 + cg;
  int pix = (oh0 + i_loc) * 32 + ow;
  float* op = xdT + ((size_t)bn * 1024 + pix) * 64 + wv * 16;
#pragma unroll
  for (int g = 0; g < 4; ++g)
    *(float4*)(op + g * 4) = make_float4(acc[g * 4 + 0], acc[g * 4 + 1],
                                         acc[g * 4 + 2], acc[g * 4 + 3]);
}

// ---------------- 2. QKV gemm coarse: xdT staging + transposed W ---------------
__global__ __launch_bounds__(192) void k_qkv_coarse(const float* __restrict__ xdT,
    const float* __restrict__ wT, const float* __restrict__ bias,
    float* __restrict__ q, float* __restrict__ k, float* __restrict__ v) {
  int row = blockIdx.x;              // bn*1024 + i
  int bn = row >> 10, i = row & 1023;
  __shared__ float t[64];
  if (threadIdx.x < 64)
    t[threadIdx.x] = xdT[((size_t)bn * 1024 + i) * 64 + threadIdx.x];
  __syncthreads();
  int e = threadIdx.x;               // 0..191
  float acc = bias[e];
  const float* wp = wT + e;
#pragma unroll
  for (int d = 0; d < 64; ++d) acc = fmaf(t[d], wp[d * 192], acc);
  float* dst = (e < 64) ? q : (e < 128) ? k : v;
  dst[(size_t)row * 64 + (e & 63)] = acc;
}

// ---------------- 3. QKV gemm topk: coutT staging + transposed W ---------------
__global__ __launch_bounds__(192) void k_qkv_topk(const float* __restrict__ coutT,
    const int* __restrict__ idx, const float* __restrict__ wT, const float* __restrict__ bias,
    float* __restrict__ q, float* __restrict__ k, float* __restrict__ v) {
  int row = blockIdx.x;              // bn*1024 + t
  int bn = row >> 10, t = row & 1023;
  int kk = t >> 2, ab = t & 3;
  int a = ab >> 1, bi = ab & 1;
  __shared__ float tl[64];
  __shared__ int ps;
  if (threadIdx.x == 0) ps = idx[bn * 256 + kk] & 1023;
  __syncthreads();
  int p = ps;
  int sh = (p >> 5) * 2 + a, sw = (p & 31) * 2 + bi;
  if (threadIdx.x < 64)
    tl[threadIdx.x] = coutT[((size_t)bn * 4096 + sh * 64 + sw) * 64 + threadIdx.x];
  __syncthreads();
  int e = threadIdx.x;
  float acc = bias[e];
  const float* wp = wT + e;
#pragma unroll
  for (int d = 0; d < 64; ++d) acc = fmaf(tl[d], wp[d * 192], acc);
  float* dst = (e < 64) ? q : (e < 128) ? k : v;
  dst[(size_t)row * 64 + (e & 63)] = acc;
}

// ---------------- 4. attention v3 (+ attT transposed output when SCORE) --------
template <bool SCORE>
__global__ __launch_bounds__(256) void k_attn3(
    const float* __restrict__ Q, const float* __restrict__ K,
    const float* __restrict__ V, float* __restrict__ O,
    float* __restrict__ spart, float* __restrict__ attT) {
  int bn = blockIdx.x >> 4;
  int it = blockIdx.x & 15;
  int tid = threadIdx.x;
  int rowgrp = tid >> 4;        // 0..15
  int colgrp = tid & 15;        // 0..15
  int i0 = rowgrp * 4;
  int j0 = colgrp * 4;
  const float* qb = Q + (size_t)bn * 65536;
  const float* kb = K + (size_t)bn * 65536;
  const float* vb = V + (size_t)bn * 65536;
  int ibase = it * 64;

  __shared__ float Ks[64][68];   // [d][i] transposed
  __shared__ float QP[64][68];   // Q transposed [d][j], reused as P [j][i]
  __shared__ float Vs[64][68];   // [j][d] natural
  __shared__ float sacc[1024];

  if (SCORE)
    for (int i = tid; i < 1024; i += 256) sacc[i] = 0.f;

  {
    int r = tid >> 4, c4 = tid & 15;
#pragma unroll
    for (int p4 = 0; p4 < 4; ++p4) {
      int i = p4 * 16 + r;
      float4 kv = *(const float4*)(kb + (size_t)(ibase + i) * 64 + c4 * 4);
      Ks[c4 * 4 + 0][i] = kv.x;
      Ks[c4 * 4 + 1][i] = kv.y;
      Ks[c4 * 4 + 2][i] = kv.z;
      Ks[c4 * 4 + 3][i] = kv.w;
    }
  }

  float m[4], l[4];
#pragma unroll
  for (int a = 0; a < 4; ++a) { m[a] = -3.0e38f; l[a] = 0.f; }

  for (int jt = 0; jt < 16; ++jt) {
    __syncthreads();
    {
      int r = tid >> 4, c4 = tid & 15;
#pragma unroll
      for (int p4 = 0; p4 < 4; ++p4) {
        int j = p4 * 16 + r;
        float4 qv = *(const float4*)(qb + (size_t)(jt * 64 + j) * 64 + c4 * 4);
        QP[c4 * 4 + 0][j] = qv.x;
        QP[c4 * 4 + 1][j] = qv.y;
        QP[c4 * 4 + 2][j] = qv.z;
        QP[c4 * 4 + 3][j] = qv.w;
      }
    }
    __syncthreads();
    float s[4][4];
#pragma unroll
    for (int a = 0; a < 4; ++a)
#pragma unroll
      for (int b = 0; b < 4; ++b) s[a][b] = 0.f;
#pragma unroll 4
    for (int d = 0; d < 64; ++d) {
      float4 kv = *(const float4*)&Ks[d][i0];
      float4 qv = *(const float4*)&QP[d][j0];
      s[0][0] = fmaf(kv.x, qv.x, s[0][0]); s[0][1] = fmaf(kv.x, qv.y, s[0][1]);
      s[0][2] = fmaf(kv.x, qv.z, s[0][2]); s[0][3] = fmaf(kv.x, qv.w, s[0][3]);
      s[1][0] = fmaf(kv.y, qv.x, s[1][0]); s[1][1] = fmaf(kv.y, qv.y, s[1][1]);
      s[1][2] = fmaf(kv.y, qv.z, s[1][2]); s[1][3] = fmaf(kv.y, qv.w, s[1][3]);
      s[2][0] = fmaf(kv.z, qv.x, s[2][0]); s[2][1] = fmaf(kv.z, qv.y, s[2][1]);
      s[2][2] = fmaf(kv.z, qv.z, s[2][2]); s[2][3] = fmaf(kv.z, qv.w, s[2][3]);
      s[3][0] = fmaf(kv.w, qv.x, s[3][0]); s[3][1] = fmaf(kv.w, qv.y, s[3][1]);
      s[3][2] = fmaf(kv.w, qv.z, s[3][2]); s[3][3] = fmaf(kv.w, qv.w, s[3][3]);
    }
#pragma unroll
    for (int a = 0; a < 4; ++a) {
      float tm = fmaxf(fmaxf(s[a][0], s[a][1]), fmaxf(s[a][2], s[a][3]));
#pragma unroll
      for (int off = 1; off <= 8; off <<= 1) tm = fmaxf(tm, __shfl_xor(tm, off, 64));
      float mn = fmaxf(m[a], tm);
      float ts = ((expf(s[a][0] - mn) + expf(s[a][1] - mn)) +
                  expf(s[a][2] - mn)) + expf(s[a][3] - mn);
#pragma unroll
      for (int off = 1; off <= 8; off <<= 1) ts += __shfl_xor(ts, off, 64);
      l[a] = l[a] * expf(m[a] - mn) + ts;
      m[a] = mn;
    }
  }
  float inv[4];
#pragma unroll
  for (int a = 0; a < 4; ++a) inv[a] = 1.f / l[a];

  float accO[4][4];
#pragma unroll
  for (int a = 0; a < 4; ++a)
#pragma unroll
    for (int b = 0; b < 4; ++b) accO[a][b] = 0.f;

  for (int jt = 0; jt < 16; ++jt) {
    __syncthreads();
    {
      int r = tid >> 4, c4 = tid & 15;
#pragma unroll
      for (int p4 = 0; p4 < 4; ++p4) {
        int j = p4 * 16 + r;
        float4 qv = *(const float4*)(qb + (size_t)(jt * 64 + j) * 64 + c4 * 4);
        QP[c4 * 4 + 0][j] = qv.x;
        QP[c4 * 4 + 1][j] = qv.y;
        QP[c4 * 4 + 2][j] = qv.z;
        QP[c4 * 4 + 3][j] = qv.w;
        float4 vv = *(const float4*)(vb + (size_t)(jt * 64 + j) * 64 + c4 * 4);
        *(float4*)&Vs[j][c4 * 4] = vv;
      }
    }
    __syncthreads();
    float s[4][4];
#pragma unroll
    for (int a = 0; a < 4; ++a)
#pragma unroll
      for (int b = 0; b < 4; ++b) s[a][b] = 0.f;
#pragma unroll 4
    for (int d = 0; d < 64; ++d) {
      float4 kv = *(const float4*)&Ks[d][i0];
      float4 qv = *(const float4*)&QP[d][j0];
      s[0][0] = fmaf(kv.x, qv.x, s[0][0]); s[0][1] = fmaf(kv.x, qv.y, s[0][1]);
      s[0][2] = fmaf(kv.x, qv.z, s[0][2]); s[0][3] = fmaf(kv.x, qv.w, s[0][3]);
      s[1][0] = fmaf(kv.y, qv.x, s[1][0]); s[1][1] = fmaf(kv.y, qv.y, s[1][1]);
      s[1][2] = fmaf(kv.y, qv.z, s[1][2]); s[1][3] = fmaf(kv.y, qv.w, s[1][3]);
      s[2][0] = fmaf(kv.z, qv.x, s[2][0]); s[2][1] = fmaf(kv.z, qv.y, s[2][1]);
      s[2][2] = fmaf(kv.z, qv.z, s[2][2]); s[2][3] = fmaf(kv.z, qv.w, s[2][3]);
      s[3][0] = fmaf(kv.w, qv.x, s[3][0]); s[3][1] = fmaf(kv.w, qv.y, s[3][1]);
      s[3][2] = fmaf(kv.w, qv.z, s[3][2]); s[3][3] = fmaf(kv.w, qv.w, s[3][3]);
    }
    float p[4][4];
#pragma unroll
    for (int a = 0; a < 4; ++a)
#pragma unroll
      for (int b = 0; b < 4; ++b) p[a][b] = expf(s[a][b] - m[a]) * inv[a];
    if (SCORE) {
#pragma unroll
      for (int b = 0; b < 4; ++b) {
        float cs = ((p[0][b] + p[1][b]) + p[2][b]) + p[3][b];
        atomicAdd(&sacc[jt * 64 + j0 + b], cs);
      }
    }
    __syncthreads();
#pragma unroll
    for (int b = 0; b < 4; ++b)
      *(float4*)&QP[j0 + b][i0] = make_float4(p[0][b], p[1][b], p[2][b], p[3][b]);
    __syncthreads();
#pragma unroll 4
    for (int j = 0; j < 64; ++j) {
      float4 pv = *(const float4*)&QP[j][i0];
      float4 vv = *(const float4*)&Vs[j][j0];
      accO[0][0] = fmaf(pv.x, vv.x, accO[0][0]); accO[0][1] = fmaf(pv.x, vv.y, accO[0][1]);
      accO[0][2] = fmaf(pv.x, vv.z, accO[0][2]); accO[0][3] = fmaf(pv.x, vv.w, accO[0][3]);
      accO[1][0] = fmaf(pv.y, vv.x, accO[1][0]); accO[1][1] = fmaf(pv.y, vv.y, accO[1][1]);
      accO[1][2] = fmaf(pv.y, vv.z, accO[1][2]); accO[1][3] = fmaf(pv.y, vv.w, accO[1][3]);
      accO[2][0] = fmaf(pv.z, vv.x, accO[2][0]); accO[2][1] = fmaf(pv.z, vv.y, accO[2][1]);
      accO[2][2] = fmaf(pv.z, vv.z, accO[2][2]); accO[2][3] = fmaf(pv.z, vv.w, accO[2][3]);
      accO[3][0] = fmaf(pv.w, vv.x, accO[3][0]); accO[3][1] = fmaf(pv.w, vv.y, accO[3][1]);
      accO[3][2] = fmaf(pv.w, vv.z, accO[3][2]); accO[3][3] = fmaf(pv.w, vv.w, accO[3][3]);
    }
  }
#pragma unroll
  for (int a = 0; a < 4; ++a) {
    float4 o4 = make_float4(accO[a][0], accO[a][1], accO[a][2], accO[a][3]);
    *(float4*)(O + ((size_t)bn * 1024 + ibase + i0 + a) * 64 + j0) = o4;
  }
  if (SCORE) {
#pragma unroll
    for (int a = 0; a < 4; ++a)
#pragma unroll
      for (int b = 0; b < 4; ++b)
        attT[((size_t)bn * 64 + j0 + b) * 1024 + ibase + i0 + a] = accO[a][b];
    __syncthreads();
    for (int i = tid; i < 1024; i += 256)
      spart[((size_t)bn * 16 + it) * 1024 + i] = sacc[i];
  }
}

// ---------------- 5. deterministic score reduction (16 partials) ----------------
__global__ __launch_bounds__(256) void k_score_reduce(const float* __restrict__ part,
                                                      float* __restrict__ score) {
  int j = blockIdx.x * 256 + threadIdx.x;   // 0..32767
  int bn = j >> 10, jj = j & 1023;
  float s = 0.f;
  for (int g = 0; g < 16; ++g) s += part[((size_t)bn * 16 + g) * 1024 + jj];
  score[j] = s;
}

// ---------------- 5b. default-init idx ----------------
__global__ __launch_bounds__(256) void k_idx_init(int* __restrict__ idx) {
  int j = blockIdx.x * 256 + threadIdx.x;
  idx[j] = j & 255;
}

// ---------------- 6. top-K by rank ----------------
__global__ __launch_bounds__(1024) void k_topk(const float* __restrict__ score,
                                               int* __restrict__ idxout) {
  int bn = blockIdx.x;
  int t = threadIdx.x;
  __shared__ float s[1024];
  s[t] = score[bn * 1024 + t];
  __syncthreads();
  float my = s[t];
  int rank = 0;
  for (int j = 0; j < 1024; ++j) {
    float o = s[j];
    rank += (o > my) || (o == my && j < t);
  }
  if (rank < 256) idxout[bn * 256 + rank] = t;
}

// ---------------- 7. transposed conv v4: per-lane px, SGPR weights -------------
__global__ __launch_bounds__(256) void k_conv_up4(const float* __restrict__ attT,
    const float* __restrict__ wt, const float* __restrict__ bias,
    float* __restrict__ cout, float* __restrict__ coutT) {
  int blk = blockIdx.x;              // ((b*4+cls)*4 + cg)*16 + ip
  int ip = blk & 15;
  int cg = (blk >> 4) & 3;
  int cls = (blk >> 6) & 3;
  int b = blk >> 8;
  int r = cls >> 1, s = cls & 1;
  int i0 = ip * 2;
  int t = threadIdx.x;
  int wv = t >> 6, lane = t & 63;
  int co0w = __builtin_amdgcn_readfirstlane(cg * 64 + wv * 16);
  int i_loc = lane >> 5;
  int jL = lane & 31;

  __shared__ float xs[8][3][34];

  float acc[16];
#pragma unroll
  for (int cc = 0; cc < 16; ++cc) acc[cc] = bias[co0w + cc];

  int rbase = i0 + r;
  const float* ab = attT + (size_t)b * 4 * 65536;

  for (int ci0 = 0; ci0 < 256; ci0 += 8) {
    __syncthreads();
    for (int idx = t; idx < 8 * 99; idx += 256) {
      int cl = idx / 99;
      int rem = idx - cl * 99;
      int rho = rem / 33;
      int c = rem - rho * 33;
      int ih = rbase + rho - 1;
      int iw = c - 1 + s;
      int ci = ci0 + cl;
      int n = ci >> 6, d = ci & 63;
      float v = 0.f;
      if ((unsigned)ih < 32u && (unsigned)iw < 32u)
        v = ab[((size_t)n * 64 + d) * 1024 + ih * 32 + iw];
      xs[cl][rho][c] = v;
    }
    __syncthreads();
#pragma unroll
    for (int cl = 0; cl < 8; ++cl) {
      int ci = ci0 + cl;
      float xA0 = xs[cl][i_loc + 1][jL];
      float xA1 = xs[cl][i_loc + 1][jL + 1];
      float xB0 = xs[cl][i_loc][jL];
      float xB1 = xs[cl][i_loc][jL + 1];
      const float* wp = wt + ((size_t)(cls * 4) * 256 + ci) * 256 + co0w;
#pragma unroll
      for (int g = 0; g < 4; ++g) {
        float4 w0 = *(const float4*)(wp + g * 4);
        float4 w1 = *(const float4*)(wp + 65536 + g * 4);
        float4 w2 = *(const float4*)(wp + 131072 + g * 4);
        float4 w3 = *(const float4*)(wp + 196608 + g * 4);
        // per-acc order: tap0 (xA1), tap1 (xA0), tap2 (xB1), tap3 (xB0)
        acc[g * 4 + 0] = fmaf(xB0, w3.x, fmaf(xB1, w2.x, fmaf(xA0, w1.x, fmaf(xA1, w0.x, acc[g * 4 + 0]))));
        acc[g * 4 + 1] = fmaf(xB0, w3.y, fmaf(xB1, w2.y, fmaf(xA0, w1.y, fmaf(xA1, w0.y, acc[g * 4 + 1]))));
        acc[g * 4 + 2] = fmaf(xB0, w3.z, fmaf(xB1, w2.z, fmaf(xA0, w1.z, fmaf(xA1, w0.z, acc[g * 4 + 2]))));
        acc[g * 4 + 3] = fmaf(xB0, w3.w, fmaf(xB1, w2.w, fmaf(xA0, w1.w, fmaf(xA1, w0.w, acc[g * 4 + 3]))));
      }
    }
  }
  int oh = 2 * (i0 + i_loc) + r;
  int ow = 2 * jL + s;
#pragma unroll
  for (int cc = 0; cc < 16; ++cc)
    cout[((size_t)b * 256 + co0w + cc) * 4096 + oh * 64 + ow] = acc[cc];
  int bn = b * 4 + cg;
  float* op = coutT + ((size_t)bn * 4096 + oh * 64 + ow) * 64 + wv * 16;
#pragma unroll
  for (int g = 0; g < 4; ++g)
    *(float4*)(op + g * 4) = make_float4(acc[g * 4 + 0], acc[g * 4 + 1],
                                         acc[g * 4 + 2], acc[g * 4 + 3]);
}

// ---------------- 8. y = coarse_out + region ----------------
__global__ __launch_bounds__(256) void k_ybuild(const float* __restrict__ cout,
                                                float* __restrict__ y) {
  size_t e = (size_t)blockIdx.x * 256 + threadIdx.x;
  int flat = (int)(e & 4095);
  size_t bc = e >> 12;
  int p = flat >> 2, ab = flat & 3;
  int a = ab >> 1, bi = ab & 1;
  int src = ((p >> 5) * 2 + a) * 64 + (p & 31) * 2 + bi;
  const float* cb = cout + bc * 4096;
  y[e] = cb[flat] + cb[src];
}

// ---------------- 9. scatter-add attended tokens ----------------
__global__ __launch_bounds__(256) void k_scatter(const float* __restrict__ out2,
    const int* __restrict__ idx, float* __restrict__ y) {
  int e = blockIdx.x * 256 + threadIdx.x;
  int d = e & 63;
  int r = e >> 6;
  int ab = r & 3;
  int r2 = r >> 2;
  int kk = r2 & 255;
  int bn = r2 >> 8;
  int b = bn >> 2, n = bn & 3;
  int p = idx[bn * 256 + kk] & 1023;
  int flat = p * 4 + ab;
  int t = kk * 4 + ab;
  y[((size_t)(b * 256 + n * 64 + d)) * 4096 + flat] +=
      out2[((size_t)bn * 1024 + t) * 64 + d];
}

// ---------------- 10. depthwise 3x3 + BN + relu6 ----------------
__global__ __launch_bounds__(256) void k_dw(const float* __restrict__ y,
    const float* __restrict__ w, const float* __restrict__ g, const float* __restrict__ bb,
    const float* __restrict__ mm, const float* __restrict__ vv, float* __restrict__ t1) {
  size_t e = (size_t)blockIdx.x * 256 + threadIdx.x;
  int pix = (int)(e & 4095);
  int c = (int)((e >> 12) & 255);
  int oh = pix >> 6, ow = pix & 63;
  const float* yb = y + (e - pix);
  float acc = 0.f;
#pragma unroll
  for (int kh = 0; kh < 3; ++kh) {
    int ih = oh - 1 + kh;
    if ((unsigned)ih >= 64u) continue;
#pragma unroll
    for (int kw = 0; kw < 3; ++kw) {
      int iw = ow - 1 + kw;
      if ((unsigned)iw >= 64u) continue;
      acc = fmaf(yb[ih * 64 + iw], w[c * 9 + kh * 3 + kw], acc);
    }
  }
  float s = g[c] * rsqrtf(vv[c] + 1e-5f);
  float val = acc * s + (bb[c] - mm[c] * s);
  t1[e] = fminf(fmaxf(val, 0.f), 6.f);
}

// ---------------- 11. pointwise v2: 4 co per block ----------------
__global__ __launch_bounds__(256) void k_pw2(const float* __restrict__ t1,
    const float* __restrict__ w, const float* __restrict__ g, const float* __restrict__ bb,
    const float* __restrict__ mm, const float* __restrict__ vv, float* __restrict__ out) {
  int blk = blockIdx.x;              // (b*64 + cog)*4 + tile
  int tile = blk & 3;
  int cog = (blk >> 2) & 63;
  int b = blk >> 8;
  int co0 = cog * 4;
  int t = threadIdx.x;
  __shared__ float wl[256][4];
  for (int idx = t; idx < 1024; idx += 256) {
    int cof = idx >> 8;
    int ci = idx & 255;
    wl[ci][cof] = w[(co0 + cof) * 256 + ci];
  }
  __syncthreads();
  int px0 = tile * 1024 + t * 4;
  const float* tb = t1 + (size_t)b * 256 * 4096 + px0;
  float acc[4][4];
#pragma unroll
  for (int a = 0; a < 4; ++a)
#pragma unroll
    for (int jj = 0; jj < 4; ++jj) acc[a][jj] = 0.f;
  for (int ci = 0; ci < 256; ++ci) {
    float4 tv = *(const float4*)(tb + (size_t)ci * 4096);
    float4 wv = *(const float4*)&wl[ci][0];
    acc[0][0] = fmaf(tv.x, wv.x, acc[0][0]); acc[0][1] = fmaf(tv.y, wv.x, acc[0][1]);
    acc[0][2] = fmaf(tv.z, wv.x, acc[0][2]); acc[0][3] = fmaf(tv.w, wv.x, acc[0][3]);
    acc[1][0] = fmaf(tv.x, wv.y, acc[1][0]); acc[1][1] = fmaf(tv.y, wv.y, acc[1][1]);
    acc[1][2] = fmaf(tv.z, wv.y, acc[1][2]); acc[1][3] = fmaf(tv.w, wv.y, acc[1][3]);
    acc[2][0] = fmaf(tv.x, wv.z, acc[2][0]); acc[2][1] = fmaf(tv.y, wv.z, acc[2][1]);
    acc[2][2] = fmaf(tv.z, wv.z, acc[2][2]); acc[2][3] = fmaf(tv.w, wv.z, acc[2][3]);
    acc[3][0] = fmaf(tv.x, wv.w, acc[3][0]); acc[3][1] = fmaf(tv.y, wv.w, acc[3][1]);
    acc[3][2] = fmaf(tv.z, wv.w, acc[3][2]); acc[3][3] = fmaf(tv.w, wv.w, acc[3][3]);
  }
#pragma unroll
  for (int a = 0; a < 4; ++a) {
    int co = co0 + a;
    float s = g[co] * rsqrtf(vv[co] + 1e-5f);
    float bias = bb[co] - mm[co] * s;
    float4 o4;
    o4.x = fminf(fmaxf(acc[a][0] * s + bias, 0.f), 6.f);
    o4.y = fminf(fmaxf(acc[a][1] * s + bias, 0.f), 6.f);
    o4.z = fminf(fmaxf(acc[a][2] * s + bias, 0.f), 6.f);
    o4.w = fminf(fmaxf(acc[a][3] * s + bias, 0.f), 6.f);
    *(float4*)(out + ((size_t)(b * 256 + co)) * 4096 + px0) = o4;
  }
}

// ---------------- launcher ----------------
extern "C" void kernel_launch(void* const* d_in, const int* in_sizes, int n_in,
                              void* d_out, int out_size, void* d_ws, size_t ws_size,
                              hipStream_t stream) {
  if (ws_size < WS_FLOATS * sizeof(float)) return;

  const float* x      = (const float*)d_in[0];
  const float* down_w = (const float*)d_in[1];
  const float* down_b = (const float*)d_in[2];
  const float* up_w   = (const float*)d_in[3];
  const float* up_b   = (const float*)d_in[4];
  const float* cqkv_w = (const float*)d_in[5];
  const float* cqkv_b = (const float*)d_in[6];
  const float* tqkv_w = (const float*)d_in[7];
  const float* tqkv_b = (const float*)d_in[8];
  const float* dww    = (const float*)d_in[9];
  const float* bn1g   = (const float*)d_in[10];
  const float* bn1b   = (const float*)d_in[11];
  const float* bn1m   = (const float*)d_in[12];
  const float* bn1v   = (const float*)d_in[13];
  const float* pww    = (const float*)d_in[14];
  const float* bn2g   = (const float*)d_in[15];
  const float* bn2b   = (const float*)d_in[16];
  const float* bn2m   = (const float*)d_in[17];
  const float* bn2v   = (const float*)d_in[18];

  float* ws    = (float*)d_ws;
  float* xdT   = ws + OFF_XD;
  float* q     = ws + OFF_Q;
  float* k     = ws + OFF_K;
  float* v     = ws + OFF_V;
  float* att   = ws + OFF_ATT;
  float* spart = ws + OFF_SPART;
  float* score = ws + OFF_SCORE;
  int*   idx   = (int*)(ws + OFF_IDX);
  float* cout  = ws + OFF_COUT;
  float* y     = ws + OFF_Y;
  float* t1    = ws + OFF_T1;
  float* dwt   = ws + OFF_SPART;             // dead after k_conv_down4
  float* wT_c  = ws + OFF_SPART + 1048576;   // 12288 fl
  float* wT_t  = ws + OFF_SPART + 1060864;   // 12288 fl
  float* attT  = ws + OFF_SPART + 2097152;   // upper half of spart region
  float* wt    = ws + OFF_XD;                // xdT dead after k_qkv_coarse
  float* coutT = ws + OFF_T1;                // t1 region dead until k_dw

  k_wt_dn<<<4096, 256, 0, stream>>>(down_w, dwt);
  k_wt_qkv<<<48, 256, 0, stream>>>(cqkv_w, wT_c);
  k_wt_qkv<<<48, 256, 0, stream>>>(tqkv_w, wT_t);
  k_conv_down4<<<512, 256, 0, stream>>>(x, dwt, down_b, xdT);
  k_qkv_coarse<<<32768, 192, 0, stream>>>(xdT, wT_c, cqkv_b, q, k, v);
  k_wt_up<<<4096, 256, 0, stream>>>(up_w, wt);          // overwrites xdT region
  k_attn3<true><<<512, 256, 0, stream>>>(q, k, v, att, spart, attT);
  k_score_reduce<<<128, 256, 0, stream>>>(spart, score);
  k_idx_init<<<32, 256, 0, stream>>>(idx);
  k_topk<<<32, 1024, 0, stream>>>(score, idx);
  k_conv_up4<<<2048, 256, 0, stream>>>(attT, wt, up_b, cout, coutT);
  k_qkv_topk<<<32768, 192, 0, stream>>>(coutT, idx, wT_t, tqkv_b, q, k, v);
  k_attn3<false><<<512, 256, 0, stream>>>(q, k, v, att, spart, attT);
  k_ybuild<<<32768, 256, 0, stream>>>(cout, y);
  k_scatter<<<8192, 256, 0, stream>>>(att, idx, y);
  k_dw<<<32768, 256, 0, stream>>>(y, dww, bn1g, bn1b, bn1m, bn1v, t1);
  k_pw2<<<2048, 256, 0, stream>>>(t1, pww, bn2g, bn2b, bn2m, bn2v, (float*)d_out);
}